// Round 3
// baseline (1235.742 us; speedup 1.0000x reference)
//
#include <hip/hip_runtime.h>
#include <math.h>

#define HH 128
#define HP 64   // u32 pairs per 128-feature row

typedef __attribute__((ext_vector_type(8))) short short8;
typedef __attribute__((ext_vector_type(4))) float float4v;
typedef __attribute__((ext_vector_type(4))) unsigned uint4v;

// ---------- helpers ----------
__device__ __forceinline__ float blo(unsigned w){ return __uint_as_float(w << 16); }
__device__ __forceinline__ float bhi(unsigned w){ return __uint_as_float(w & 0xffff0000u); }
__device__ __forceinline__ unsigned short f2b(float x){
  unsigned u = __float_as_uint(x);
  u += 0x7fffu + ((u >> 16) & 1u);           // RNE to bf16
  return (unsigned short)(u >> 16);
}
__device__ __forceinline__ unsigned pack2(float a, float b){
  return (unsigned)f2b(a) | ((unsigned)f2b(b) << 16);
}
__device__ __forceinline__ float silu_f(float x){ return x / (1.f + __expf(-x)); }

// ---------- sort-by-dst kernels ----------
__global__ void hist_kernel(const int* __restrict__ dst, unsigned* __restrict__ hist, int E){
  int i = blockIdx.x * blockDim.x + threadIdx.x;
  int st = gridDim.x * blockDim.x;
  for (; i < E; i += st) atomicAdd(&hist[dst[i]], 1u);
}

__global__ void scan_block_kernel(const unsigned* __restrict__ hist,
                                  unsigned* __restrict__ offs,
                                  unsigned* __restrict__ bsums, int N){
  __shared__ unsigned s[256];
  int t = threadIdx.x, g = blockIdx.x * 256 + t;
  unsigned v = (g < N) ? hist[g] : 0u;
  s[t] = v; __syncthreads();
  for (int o = 1; o < 256; o <<= 1) {
    unsigned a = (t >= o) ? s[t - o] : 0u; __syncthreads();
    s[t] += a; __syncthreads();
  }
  unsigned incl = s[t];
  if (g < N) offs[g] = incl - v;
  if (t == 255) bsums[blockIdx.x] = incl;
}

__global__ void scan_top_kernel(unsigned* __restrict__ bsums, int NB){
  __shared__ unsigned s[256];
  int t = threadIdx.x;
  unsigned v = (t < NB) ? bsums[t] : 0u;
  s[t] = v; __syncthreads();
  for (int o = 1; o < 256; o <<= 1) {
    unsigned a = (t >= o) ? s[t - o] : 0u; __syncthreads();
    s[t] += a; __syncthreads();
  }
  unsigned incl = s[t];
  if (t < NB) bsums[t] = incl - v;           // exclusive
}

__global__ void scan_add_kernel(unsigned* __restrict__ offs,
                                const unsigned* __restrict__ bsums, int N){
  int g = blockIdx.x * 256 + threadIdx.x;
  if (g < N) offs[g] += bsums[blockIdx.x];
}

__global__ void scatter_kernel(const int* __restrict__ dst, unsigned* __restrict__ offs,
                               int* __restrict__ perm, int E){
  int i = blockIdx.x * blockDim.x + threadIdx.x;
  int st = gridDim.x * blockDim.x;
  for (; i < E; i += st) {
    unsigned pos = atomicAdd(&offs[dst[i]], 1u);
    perm[pos] = i;
  }
}

// ---------- per-node precompute: A = h@W[0:128] + bias, B = h@W[128:256] ----------
__global__ __launch_bounds__(256) void precompute_kernel(
    const float* __restrict__ h, const float* __restrict__ W,
    const float* __restrict__ bias,
    unsigned* __restrict__ Aout, unsigned* __restrict__ Bout, int N)
{
  __shared__ unsigned Wl[256 * HP];           // 64 KB
  int t = threadIdx.x;
  const float2* W2 = (const float2*)W;
  for (int i = t; i < 256 * HP; i += 256) {
    float2 w = W2[i];
    Wl[i] = pack2(w.x, w.y);
  }
  __syncthreads();

  int wid = blockIdx.x * 4 + (t >> 6);
  int nw  = gridDim.x * 4;
  int jp  = t & 63;
  for (int n = wid; n < N; n += nw) {
    const float4* hn = (const float4*)(h + (size_t)n * HH);
    float a0 = 0.f, a1 = 0.f, b0 = 0.f, b1 = 0.f;
    #pragma unroll 8
    for (int k4 = 0; k4 < 32; ++k4) {
      float4 hv = hn[k4];
      float xs[4] = {hv.x, hv.y, hv.z, hv.w};
      #pragma unroll
      for (int u = 0; u < 4; ++u) {
        int k = 4 * k4 + u;
        unsigned wa = Wl[k * HP + jp];
        unsigned wb = Wl[(128 + k) * HP + jp];
        a0 += xs[u] * blo(wa); a1 += xs[u] * bhi(wa);
        b0 += xs[u] * blo(wb); b1 += xs[u] * bhi(wb);
      }
    }
    a0 += bias[2 * jp]; a1 += bias[2 * jp + 1];
    Aout[(size_t)n * HP + jp] = pack2(a0, a1);
    Bout[(size_t)n * HP + jp] = pack2(b0, b1);
  }
}

// ---------- MFMA edge kernels, wave-private 16-edge tiles, NO inner barriers ----------
// MODE 0 = edge MLP (att -> h_agg), MODE 1 = coord MLP (-> x_agg)
template<int MODE>
__global__ __launch_bounds__(256) void edge_kernel(
    const unsigned* __restrict__ Apart, const unsigned* __restrict__ Bpart,
    const float* __restrict__ W1,       // (276,128); rows 256..275 = tail
    const float* __restrict__ W2, const float* __restrict__ b2,
    const float* __restrict__ Wv, const float* __restrict__ ba_p,
    const int* __restrict__ src, const int* __restrict__ dst,
    const int* __restrict__ perm,
    const float* __restrict__ coords, const float* __restrict__ afeat,
    float* __restrict__ out_agg, int E)
{
  __shared__ __align__(16) unsigned short W2Ts[128 * 136]; // 34.8 KB, n-major bf16
  __shared__ __align__(16) unsigned mhl[4][16 * 68];       // 17.4 KB wave-private
  __shared__ __align__(16) float tails[4][16 * 20];        // 5.1 KB
  __shared__ float difl[4][64];                            // dx,dy,dz,rad per edge
  __shared__ int   sll[4][16], dll[4][16], pel[4][16];

  const int t = threadIdx.x;
  const int lane = t & 63;
  const int w = t >> 6;
  const int col = lane & 15;
  const int quad = lane >> 4;

  // stage W2 transposed as bf16 (once per block)
  for (int i = t; i < 128 * 128; i += 256) {
    int k = i >> 7, n = i & 127;
    W2Ts[n * 136 + k] = f2b(W2[i]);
  }
  // per-lane constants
  float wt0[20], wt1[20];
  #pragma unroll
  for (int k = 0; k < 20; ++k) {
    wt0[k] = W1[(256 + k) * 128 + 2 * lane];
    wt1[k] = W1[(256 + k) * 128 + 2 * lane + 1];
  }
  float b2reg[8], wvreg[8];
  #pragma unroll
  for (int nt = 0; nt < 8; ++nt) {
    int n = nt * 16 + col;
    b2reg[nt] = b2[n];
    wvreg[nt] = Wv[n];
  }
  const float bav = (MODE == 0) ? ba_p[0] : 0.f;
  __syncthreads();                            // W2Ts ready (only block-wide barrier)

  const int ntiles = (E + 15) >> 4;
  const int wstride = gridDim.x * 4;
  for (int tile = blockIdx.x * 4 + w; tile < ntiles; tile += wstride) {
    const int e0 = tile * 16;

    // ---- stage per-edge scalars (wave-private; DS ops are wave-in-order) ----
    if (lane < 16) {
      int eg = e0 + lane;
      bool v = eg < E;
      int pe = v ? perm[eg] : 0;
      int s = v ? src[pe] : 0;
      int d = v ? dst[pe] : 0;
      pel[w][lane] = pe; sll[w][lane] = s; dll[w][lane] = d;
      float dx = coords[s*3+0] - coords[d*3+0];
      float dy = coords[s*3+1] - coords[d*3+1];
      float dz = coords[s*3+2] - coords[d*3+2];
      if (!v) { dx = 0.f; dy = 0.f; dz = 0.f; }
      float rad = sqrtf(dx*dx + dy*dy + dz*dz);
      difl[w][lane*4+0] = dx; difl[w][lane*4+1] = dy;
      difl[w][lane*4+2] = dz; difl[w][lane*4+3] = rad;
      tails[w][lane*20+0] = rad;      tails[w][lane*20+1] = fabsf(dx);
      tails[w][lane*20+2] = fabsf(dy); tails[w][lane*20+3] = fabsf(dz);
    }
    {
      int e = lane >> 2;
      int fb = (lane & 3) * 4;
      int pe = pel[w][e];                     // broadcast LDS read
      float4 av = *(const float4*)(afeat + (size_t)pe * 16 + fb);
      *(float4*)&tails[w][e * 20 + 4 + fb] = av;
    }

    // ---- phase A: layer-1 assembly + silu -> mhl (A-operand layout) ----
    unsigned wa[16], wb[16];
    #pragma unroll
    for (int i = 0; i < 16; ++i) {
      wa[i] = Apart[(size_t)sll[w][i] * HP + lane];
      wb[i] = Bpart[(size_t)dll[w][i] * HP + lane];
    }
    #pragma unroll
    for (int i = 0; i < 16; ++i) {
      float t0 = blo(wa[i]) + blo(wb[i]);
      float t1 = bhi(wa[i]) + bhi(wb[i]);
      const float4* tp = (const float4*)&tails[w][i * 20];
      float4 v0 = tp[0], v1 = tp[1], v2 = tp[2], v3 = tp[3], v4 = tp[4];
      float tv[20] = {v0.x,v0.y,v0.z,v0.w, v1.x,v1.y,v1.z,v1.w,
                      v2.x,v2.y,v2.z,v2.w, v3.x,v3.y,v3.z,v3.w,
                      v4.x,v4.y,v4.z,v4.w};
      #pragma unroll
      for (int k = 0; k < 20; ++k) { t0 += tv[k] * wt0[k]; t1 += tv[k] * wt1[k]; }
      mhl[w][i * 68 + lane] = pack2(silu_f(t0), silu_f(t1));
    }

    // ---- phase B: layer 2 via MFMA (this wave covers all 128 outputs) ----
    float4v acc[8] = {{0,0,0,0},{0,0,0,0},{0,0,0,0},{0,0,0,0},
                      {0,0,0,0},{0,0,0,0},{0,0,0,0},{0,0,0,0}};
    const unsigned* mw = mhl[w];
    #pragma unroll
    for (int ks = 0; ks < 4; ++ks) {
      short8 af = __builtin_bit_cast(short8, *(const uint4v*)(mw + col*68 + ks*16 + quad*4));
      #pragma unroll
      for (int nt = 0; nt < 8; ++nt) {
        const unsigned short* bp = &W2Ts[(nt*16 + col)*136 + ks*32 + quad*8];
        short8 bf = __builtin_bit_cast(short8, *(const uint4v*)bp);
        acc[nt] = __builtin_amdgcn_mfma_f32_16x16x32_bf16(af, bf, acc[nt], 0, 0, 0);
      }
    }

    // ---- epilogue: bias+silu, head dot, 16-lane reduce, run-combined scatter ----
    float vv[8][4];
    float p[4] = {0.f, 0.f, 0.f, 0.f};
    #pragma unroll
    for (int nt = 0; nt < 8; ++nt)
      #pragma unroll
      for (int r = 0; r < 4; ++r) {
        float v = silu_f(acc[nt][r] + b2reg[nt]);
        vv[nt][r] = v;
        p[r] += v * wvreg[nt];
      }
    #pragma unroll
    for (int r = 0; r < 4; ++r) {
      #pragma unroll
      for (int off = 1; off < 16; off <<= 1) p[r] += __shfl_xor(p[r], off, 64);
    }
    int dq[4];
    #pragma unroll
    for (int r = 0; r < 4; ++r) dq[r] = dll[w][quad*4 + r];

    if (MODE == 0) {
      float att[4];
      #pragma unroll
      for (int r = 0; r < 4; ++r) {
        int eg = e0 + quad*4 + r;
        att[r] = (eg < E) ? 1.f / (1.f + __expf(-(p[r] + bav))) : 0.f;
      }
      #pragma unroll
      for (int nt = 0; nt < 8; ++nt) {
        int n = nt*16 + col;
        float accm = att[0] * vv[nt][0];
        int dprev = dq[0];
        #pragma unroll
        for (int r = 1; r < 4; ++r) {
          float val = att[r] * vv[nt][r];
          if (dq[r] == dprev) accm += val;     // quad-uniform branch
          else {
            unsafeAtomicAdd(&out_agg[(size_t)dprev * HH + n], accm);
            dprev = dq[r]; accm = val;
          }
        }
        unsafeAtomicAdd(&out_agg[(size_t)dprev * HH + n], accm);
      }
    } else {
      if (col < 3) {
        float accm = 0.f;
        int dprev = dq[0];
        #pragma unroll
        for (int r = 0; r < 4; ++r) {
          int e = quad*4 + r;
          int eg = e0 + e;
          float rad = difl[w][e*4 + 3];
          float fac = (eg < E) ? p[r] / (rad + 1.f) : 0.f;
          float val = fac * difl[w][e*4 + col];
          if (r > 0 && dq[r] != dprev) {
            unsafeAtomicAdd(&out_agg[(size_t)dprev * 3 + col], accm);
            dprev = dq[r]; accm = 0.f;
          }
          accm += val;
        }
        unsafeAtomicAdd(&out_agg[(size_t)dprev * 3 + col], accm);
      }
    }
    // no barrier: wave-private LDS + in-order DS ops make next tile safe
  }
}

// ---------- node MLP layer 1 ----------
__global__ __launch_bounds__(256) void node_l1_kernel(
    const float* __restrict__ h, const float* __restrict__ h_agg,
    const float* __restrict__ Wn1, const float* __restrict__ bn1,
    unsigned* __restrict__ g, int N)
{
  __shared__ unsigned Wl[256 * HP];
  int t = threadIdx.x;
  const float2* W2 = (const float2*)Wn1;
  for (int i = t; i < 256 * HP; i += 256) { float2 w = W2[i]; Wl[i] = pack2(w.x, w.y); }
  __syncthreads();

  int wid = blockIdx.x * 4 + (t >> 6);
  int nw  = gridDim.x * 4;
  int jp  = t & 63;
  for (int n = wid; n < N; n += nw) {
    float a0 = bn1[2*jp], a1 = bn1[2*jp + 1];
    const float4* hn = (const float4*)(h + (size_t)n * HH);
    const float4* gn = (const float4*)(h_agg + (size_t)n * HH);
    #pragma unroll 4
    for (int k4 = 0; k4 < 32; ++k4) {
      float4 hv = hn[k4];
      float xs[4] = {hv.x, hv.y, hv.z, hv.w};
      #pragma unroll
      for (int u = 0; u < 4; ++u) {
        unsigned w = Wl[(4*k4 + u) * HP + jp];
        a0 += xs[u] * blo(w); a1 += xs[u] * bhi(w);
      }
    }
    #pragma unroll 4
    for (int k4 = 0; k4 < 32; ++k4) {
      float4 hv = gn[k4];
      float xs[4] = {hv.x, hv.y, hv.z, hv.w};
      #pragma unroll
      for (int u = 0; u < 4; ++u) {
        unsigned w = Wl[(128 + 4*k4 + u) * HP + jp];
        a0 += xs[u] * blo(w); a1 += xs[u] * bhi(w);
      }
    }
    g[(size_t)n * HP + jp] = pack2(silu_f(a0), silu_f(a1));
  }
}

// ---------- node MLP layer 2 ----------
__global__ __launch_bounds__(256) void node_l2_kernel(
    const unsigned* __restrict__ g, const float* __restrict__ h,
    const float* __restrict__ Wn2, const float* __restrict__ bn2,
    float* __restrict__ hout, int N)
{
  __shared__ unsigned Wl[128 * HP];
  int t = threadIdx.x;
  const float2* W2 = (const float2*)Wn2;
  for (int i = t; i < 128 * HP; i += 256) { float2 w = W2[i]; Wl[i] = pack2(w.x, w.y); }
  __syncthreads();

  int wid = blockIdx.x * 4 + (t >> 6);
  int nw  = gridDim.x * 4;
  int jp  = t & 63;
  for (int n = wid; n < N; n += nw) {
    float a0 = bn2[2*jp], a1 = bn2[2*jp + 1];
    const uint2* gn = (const uint2*)(g + (size_t)n * HP);
    #pragma unroll 4
    for (int k2 = 0; k2 < 32; ++k2) {
      uint2 gp = gn[k2];
      float x0 = blo(gp.x), x1 = bhi(gp.x), x2 = blo(gp.y), x3 = bhi(gp.y);
      unsigned w0 = Wl[(4*k2    ) * HP + jp];
      unsigned w1 = Wl[(4*k2 + 1) * HP + jp];
      unsigned w2 = Wl[(4*k2 + 2) * HP + jp];
      unsigned w3 = Wl[(4*k2 + 3) * HP + jp];
      a0 += x0*blo(w0) + x1*blo(w1) + x2*blo(w2) + x3*blo(w3);
      a1 += x0*bhi(w0) + x1*bhi(w1) + x2*bhi(w2) + x3*bhi(w3);
    }
    float2 hv = ((const float2*)h)[(size_t)n * HP + jp];
    ((float2*)hout)[(size_t)n * HP + jp] = make_float2(hv.x + a0, hv.y + a1);
  }
}

// ---------- coords_out = coords + x_agg ----------
__global__ void coords_out_kernel(const float* __restrict__ coords,
                                  const float* __restrict__ x_agg,
                                  float* __restrict__ out, int n3)
{
  int i = blockIdx.x * blockDim.x + threadIdx.x;
  if (i < n3) out[i] = coords[i] + x_agg[i];
}

extern "C" void kernel_launch(void* const* d_in, const int* in_sizes, int n_in,
                              void* d_out, int out_size, void* d_ws, size_t ws_size,
                              hipStream_t stream)
{
  const float* h      = (const float*)d_in[0];
  const float* coords = (const float*)d_in[1];
  const float* afeat  = (const float*)d_in[2];
  const int*   src    = (const int*)d_in[3];
  const int*   dst    = (const int*)d_in[4];
  const float* We1 = (const float*)d_in[5];
  const float* be1 = (const float*)d_in[6];
  const float* We2 = (const float*)d_in[7];
  const float* be2 = (const float*)d_in[8];
  const float* Wa  = (const float*)d_in[9];
  const float* ba  = (const float*)d_in[10];
  const float* Wn1 = (const float*)d_in[11];
  const float* bn1 = (const float*)d_in[12];
  const float* Wn2 = (const float*)d_in[13];
  const float* bn2 = (const float*)d_in[14];
  const float* Wc1 = (const float*)d_in[15];
  const float* bc1 = (const float*)d_in[16];
  const float* Wc2 = (const float*)d_in[17];
  const float* bc2 = (const float*)d_in[18];
  const float* Wc3 = (const float*)d_in[19];

  const int E = in_sizes[3];
  const int N = in_sizes[0] / HH;

  unsigned* A1 = (unsigned*)d_ws;
  unsigned* B1 = A1 + (size_t)N * HP;
  unsigned* Ac = B1 + (size_t)N * HP;
  unsigned* Bc = Ac + (size_t)N * HP;
  float* h_agg = (float*)(Bc + (size_t)N * HP);
  float* x_agg = h_agg + (size_t)N * HH;
  int*   perm  = (int*)(x_agg + (size_t)N * 3);
  unsigned* histb = (unsigned*)(perm + E);
  unsigned* offs  = histb + N;
  unsigned* bsums = offs + N;
  unsigned* gbuf = A1;                        // reuse after edge kernels finish

  hipMemsetAsync(histb, 0, (size_t)N * sizeof(unsigned), stream);
  hipMemsetAsync(h_agg, 0, ((size_t)N * HH + (size_t)N * 3) * sizeof(float), stream);

  // counting sort of edges by dst
  hist_kernel<<<512, 256, 0, stream>>>(dst, histb, E);
  int NB = (N + 255) / 256;
  scan_block_kernel<<<NB, 256, 0, stream>>>(histb, offs, bsums, N);
  scan_top_kernel<<<1, 256, 0, stream>>>(bsums, NB);
  scan_add_kernel<<<NB, 256, 0, stream>>>(offs, bsums, N);
  scatter_kernel<<<512, 256, 0, stream>>>(dst, offs, perm, E);

  precompute_kernel<<<512, 256, 0, stream>>>(h, We1, be1, A1, B1, N);
  precompute_kernel<<<512, 256, 0, stream>>>(h, Wc1, bc1, Ac, Bc, N);

  edge_kernel<0><<<1024, 256, 0, stream>>>(A1, B1, We1, We2, be2, Wa, ba,
                                           src, dst, perm, coords, afeat, h_agg, E);
  edge_kernel<1><<<1024, 256, 0, stream>>>(Ac, Bc, Wc1, Wc2, bc2, Wc3, nullptr,
                                           src, dst, perm, coords, afeat, x_agg, E);

  node_l1_kernel<<<512, 256, 0, stream>>>(h, h_agg, Wn1, bn1, gbuf, N);
  node_l2_kernel<<<1024, 256, 0, stream>>>(gbuf, h, Wn2, bn2, (float*)d_out, N);
  coords_out_kernel<<<(N * 3 + 255) / 256, 256, 0, stream>>>(
      coords, x_agg, (float*)d_out + (size_t)N * HH, N * 3);
}